// Round 1
// baseline (1001.687 us; speedup 1.0000x reference)
//
#include <hip/hip_runtime.h>
#include <hip/hip_bf16.h>
#include <stdint.h>

// Problem constants (from reference setup_inputs)
#define NROW 8192          // N
#define DDIM 512           // D
#define BB   8             // B
#define PP   4             // P
#define MTOT (BB*NROW)     // 65536 rows
#define KTOT (PP*DDIM)     // 2048 stacked-K

typedef __attribute__((ext_vector_type(8))) short short8;          // 8 bf16 = 4 VGPRs
typedef __attribute__((ext_vector_type(8))) unsigned short ushort8;
typedef __attribute__((ext_vector_type(4))) float floatx4;

// ---- fp32 <-> bf16 helpers (manual, RNE) ----
__device__ inline unsigned short f2bf(float f) {
    unsigned u = __float_as_uint(f);
    unsigned r = 0x7FFFu + ((u >> 16) & 1u);
    u += r;
    return (unsigned short)(u >> 16);
}
__device__ inline float bf2f(unsigned short h) {
    return __uint_as_float(((unsigned)h) << 16);
}

template <typename T> __device__ inline float loadF(const T* p);
template <> __device__ inline float loadF<float>(const float* p) { return *p; }
template <> __device__ inline float loadF<unsigned short>(const unsigned short* p) { return bf2f(*p); }

template <typename T> __device__ inline void storeF(T* p, float f);
template <> __device__ inline void storeF<float>(float* p, float f) { *p = f; }
template <> __device__ inline void storeF<unsigned short>(unsigned short* p, float f) { *p = f2bf(f); }

// ---- histogram: cnt[i][r] = multiplicity of r in groups[i] ----
__global__ void hist_kernel(const int* __restrict__ groups, float* __restrict__ cnt) {
    int t = blockIdx.x * 256 + threadIdx.x;     // 0..32767
    int i = t >> 13;                            // 8192 indices per projection
    int idx = groups[t];
    atomicAdd(&cnt[i * NROW + idx], 1.0f);
}

// ---- W transpose + bf16: Wt[i][e][d] = bf16(W[i][d][e]) ----
__global__ void transpose_w(const float* __restrict__ W, unsigned short* __restrict__ Wt) {
    int f = blockIdx.x * 256 + threadIdx.x;     // 0..4*512*512-1
    int i = f >> 18;
    int r = f & 262143;
    int d = r & 511;
    int e = r >> 9;
    Wt[f] = f2bf(W[i * 262144 + d * 512 + e]);
}

// ---- fused round GEMM ----
// dst[m,:] = src[m,:] + scale * sum_i cnt_i[m%N] * (src[m,:] @ W_i)
// Implemented as single GEMM: A_stacked(M x 2048) @ Wt_stacked(2048 x 512),
// A_stacked generated on-the-fly during LDS staging (scale row by cnt_i, cvt bf16).
// Tile: 128(M) x 128(N), BK=32, 4 waves, each wave 64x64 via 4x4 mfma_16x16x32_bf16.
template <typename SrcT, typename DstT>
__global__ __launch_bounds__(256)
void gemm_round(const SrcT* __restrict__ src, const unsigned short* __restrict__ Wt,
                const float* __restrict__ cnt, DstT* __restrict__ dst, float scale)
{
    constexpr int AS = 56;                      // LDS row stride (elems): 112B, 16B-aligned, low-conflict
    __shared__ unsigned short sA[128 * AS];
    __shared__ unsigned short sB[128 * AS];

    const int t  = threadIdx.x;
    const int m0 = blockIdx.x * 128;
    const int n0 = blockIdx.y * 128;

    // staging assignment: 2 threads per row, 16 elems each
    const int srow = t >> 1;
    const int scol = (t & 1) * 16;
    const int gm   = m0 + srow;
    const int rmod = gm & (NROW - 1);

    float cv[PP];
    #pragma unroll
    for (int i = 0; i < PP; ++i) cv[i] = cnt[i * NROW + rmod];

    const int wave = t >> 6;
    const int lane = t & 63;
    const int wm = (wave & 1) * 64;
    const int wn = (wave >> 1) * 64;
    const int lm = lane & 15;
    const int lk = (lane >> 4) * 8;             // k-offset of the 8-elem fragment chunk

    floatx4 acc[4][4] = {};

    const SrcT* arow = src + (size_t)gm * DDIM + scol;

    for (int i = 0; i < PP; ++i) {
        const float c = cv[i];
        const unsigned short* brow = Wt + i * 262144 + (n0 + srow) * 512 + scol;
        for (int kb = 0; kb < DDIM / 32; ++kb) {
            const int kk = kb * 32;
            __syncthreads();   // previous iter's fragment reads complete
            // ---- stage A: 16 elems, scale by c, cvt bf16 ----
            {
                float v[16];
                if constexpr (sizeof(SrcT) == 4) {
                    const floatx4* q = (const floatx4*)(arow + kk);
                    floatx4 q0 = q[0], q1 = q[1], q2 = q[2], q3 = q[3];
                    #pragma unroll
                    for (int j = 0; j < 4; ++j) { v[j] = q0[j]; v[4+j] = q1[j]; v[8+j] = q2[j]; v[12+j] = q3[j]; }
                } else {
                    const ushort8* q = (const ushort8*)(arow + kk);
                    ushort8 q0 = q[0], q1 = q[1];
                    #pragma unroll
                    for (int j = 0; j < 8; ++j) { v[j] = bf2f(q0[j]); v[8+j] = bf2f(q1[j]); }
                }
                ushort8 ha, hb;
                #pragma unroll
                for (int j = 0; j < 8; ++j) { ha[j] = f2bf(c * v[j]); hb[j] = f2bf(c * v[8+j]); }
                *(ushort8*)&sA[srow * AS + scol]     = ha;
                *(ushort8*)&sA[srow * AS + scol + 8] = hb;
            }
            // ---- stage B: straight bf16 copy ----
            {
                const ushort8* q = (const ushort8*)(brow + kk);
                ushort8 b0 = q[0], b1 = q[1];
                *(ushort8*)&sB[srow * AS + scol]     = b0;
                *(ushort8*)&sB[srow * AS + scol + 8] = b1;
            }
            __syncthreads();
            // ---- fragments + MFMA ----
            short8 af[4], bf[4];
            #pragma unroll
            for (int a = 0; a < 4; ++a)
                af[a] = *(const short8*)&sA[(wm + 16 * a + lm) * AS + lk];
            #pragma unroll
            for (int b = 0; b < 4; ++b)
                bf[b] = *(const short8*)&sB[(wn + 16 * b + lm) * AS + lk];
            #pragma unroll
            for (int a = 0; a < 4; ++a)
                #pragma unroll
                for (int b = 0; b < 4; ++b)
                    acc[a][b] = __builtin_amdgcn_mfma_f32_16x16x32_bf16(af[a], bf[b], acc[a][b], 0, 0, 0);
        }
    }

    // ---- epilogue: dst = src + scale*acc  (C/D: col=lane&15, row=(lane>>4)*4+reg) ----
    const int l4 = lane >> 4;
    #pragma unroll
    for (int a = 0; a < 4; ++a) {
        #pragma unroll
        for (int b = 0; b < 4; ++b) {
            #pragma unroll
            for (int q = 0; q < 4; ++q) {
                const int om = m0 + wm + 16 * a + l4 * 4 + q;
                const int on = n0 + wn + 16 * b + lm;
                const float uprev = loadF(src + (size_t)om * DDIM + on);
                storeF(dst + (size_t)om * DDIM + on, uprev + scale * acc[a][b][q]);
            }
        }
    }
}

extern "C" void kernel_launch(void* const* d_in, const int* in_sizes, int n_in,
                              void* d_out, int out_size, void* d_ws, size_t ws_size,
                              hipStream_t stream) {
    const float* x      = (const float*)d_in[0];   // (8, 8192, 512) fp32
    const float* W      = (const float*)d_in[1];   // (4, 512, 512) fp32
    const int*   groups = (const int*)d_in[2];     // (4, 512, 16) int32
    float* out = (float*)d_out;                    // (8, 8192, 512) fp32

    // workspace layout
    char* ws = (char*)d_ws;
    float*          cnt = (float*)ws;                                   // 4*8192*4   = 128 KB
    unsigned short* Wt  = (unsigned short*)(ws + 131072);               // 4*512*512*2 = 2 MB
    unsigned short* U2  = (unsigned short*)(ws + 131072 + 2097152);     // 65536*512*2 = 64 MB

    hipMemsetAsync(cnt, 0, PP * NROW * sizeof(float), stream);
    hist_kernel<<<32768 / 256, 256, 0, stream>>>(groups, cnt);
    transpose_w<<<(PP * DDIM * DDIM) / 256, 256, 0, stream>>>(W, Wt);

    dim3 grid(MTOT / 128, DDIM / 128);
    // round 1: x (fp32) -> out (fp32), scale 1
    gemm_round<float, float><<<grid, 256, 0, stream>>>(x, Wt, cnt, out, 1.0f);
    // round 2: out (fp32) -> U2 (bf16), scale 1/2
    gemm_round<float, unsigned short><<<grid, 256, 0, stream>>>(out, Wt, cnt, U2, 0.5f);
    // round 3: U2 (bf16) -> out (fp32), scale 1/3
    gemm_round<unsigned short, float><<<grid, 256, 0, stream>>>(U2, Wt, cnt, out, 1.0f / 3.0f);
}

// Round 2
// 806.537 us; speedup vs baseline: 1.2420x; 1.2420x over previous
//
#include <hip/hip_runtime.h>
#include <stdint.h>

#define NROW 8192          // N
#define DDIM 512           // D
#define BB   8             // B
#define PP   4             // P
#define MTOT (BB*NROW)     // 65536 rows

typedef __attribute__((ext_vector_type(8))) short short8;            // 8 bf16 (4 VGPRs)
typedef __attribute__((ext_vector_type(8))) unsigned short ushort8;
typedef __attribute__((ext_vector_type(4))) float floatx4;
typedef __attribute__((ext_vector_type(4))) unsigned int uintx4;

// ---- bf16 helpers ----
__device__ inline float bf2f(unsigned short h) { return __uint_as_float(((unsigned)h) << 16); }
__device__ inline unsigned short f2bf_rn(float f) {
    return (unsigned short)((__float_as_uint(f) + 0x8000u) >> 16);   // round-half-up
}
// pack two fp32 -> two bf16 in one u32 (elem0 = a, elem1 = b): 2 adds + 1 v_perm
__device__ inline unsigned pack_bf16(float a, float b) {
    unsigned ua = __float_as_uint(a) + 0x8000u;
    unsigned ub = __float_as_uint(b) + 0x8000u;
    return __builtin_amdgcn_perm(ub, ua, 0x07060302u);
}

template <typename T> __device__ inline float loadF(const T* p);
template <> __device__ inline float loadF<float>(const float* p) { return *p; }
template <> __device__ inline float loadF<unsigned short>(const unsigned short* p) { return bf2f(*p); }
template <typename T> __device__ inline void storeF(T* p, float f);
template <> __device__ inline void storeF<float>(float* p, float f) { *p = f; }
template <> __device__ inline void storeF<unsigned short>(unsigned short* p, float f) { *p = f2bf_rn(f); }

// async global->LDS, 16B per lane; LDS dest = wave-uniform base + lane*16
__device__ inline void glds16(const void* g, void* l) {
    __builtin_amdgcn_global_load_lds(
        (const __attribute__((address_space(1))) void*)g,
        (__attribute__((address_space(3))) void*)l, 16, 0, 0);
}

// load 16 contiguous source elems as fp32
template <typename SrcT> __device__ inline void loadA16(float v[16], const SrcT* p);
template <> __device__ inline void loadA16<float>(float v[16], const float* p) {
    const floatx4* q = (const floatx4*)p;
    floatx4 a = q[0], b = q[1], c = q[2], d = q[3];
    #pragma unroll
    for (int j = 0; j < 4; ++j) { v[j]=a[j]; v[4+j]=b[j]; v[8+j]=c[j]; v[12+j]=d[j]; }
}
template <> __device__ inline void loadA16<unsigned short>(float v[16], const unsigned short* p) {
    const ushort8* q = (const ushort8*)p;
    ushort8 a = q[0], b = q[1];
    #pragma unroll
    for (int j = 0; j < 8; ++j) { v[j]=bf2f(a[j]); v[8+j]=bf2f(b[j]); }
}

// ---- histogram: cnt[i][r] = multiplicity of r in groups[i] ----
__global__ void hist_kernel(const int* __restrict__ groups, float* __restrict__ cnt) {
    int t = blockIdx.x * 256 + threadIdx.x;     // 0..32767
    int i = t >> 13;
    atomicAdd(&cnt[i * NROW + groups[t]], 1.0f);
}

// ---- W -> bf16, pre-swizzled into MFMA B-fragment order ----
// Wsw[i][kb 0..15][gtile 0..31][lane 0..63][e 0..7] = bf16(W[i][k][n])
//   n = gtile*16 + (lane&15), k = kb*32 + (lane>>4)*8 + e
// GEMM B staging then reads contiguous 1KB chunks via global_load_lds.
__global__ void transpose_w(const float* __restrict__ W, unsigned short* __restrict__ Wsw) {
    int u = blockIdx.x * 256 + threadIdx.x;     // 0..131071 (one 16B chunk each)
    int i    = u >> 15;
    int kb   = (u >> 11) & 15;
    int gt   = (u >> 6) & 31;
    int lane = u & 63;
    int n  = gt * 16 + (lane & 15);
    int k0 = kb * 32 + (lane >> 4) * 8;
    const float* wp = W + i * 262144 + k0 * 512 + n;
    unsigned hp[4];
    #pragma unroll
    for (int j = 0; j < 4; ++j)
        hp[j] = pack_bf16(wp[(2*j) * 512], wp[(2*j+1) * 512]);
    uintx4 w = {hp[0], hp[1], hp[2], hp[3]};
    *(uintx4*)(Wsw + (size_t)u * 8) = w;
}

// ---- fused round GEMM ----
// dst[m,:] = src[m,:] + scale * sum_i cnt_i[m%N] * (src[m,:] @ W_i)
// 128x128 tile, BK=32, 4 waves, 4x4 mfma_16x16x32_bf16 per wave.
// LDS in fragment-contiguous layout [tile][lane][8] -> conflict-free b128 reads.
template <typename SrcT, typename DstT>
__global__ __launch_bounds__(256, 3)
void gemm_round(const SrcT* __restrict__ src, const unsigned short* __restrict__ Wsw,
                const float* __restrict__ cnt, DstT* __restrict__ dst, float scale)
{
    __shared__ __align__(16) unsigned short sA[4096];   // 8 mtiles * 64 lanes * 8
    __shared__ __align__(16) unsigned short sB[4096];   // 8 ntiles * 64 lanes * 8

    const int t    = threadIdx.x;
    const int m0   = blockIdx.x * 128;
    const int nb   = blockIdx.y;                 // n0 = nb*128
    const int srow = t >> 1;                     // staged A row 0..127
    const int half = t & 1;                      // which 16-col half of the 32-wide kb chunk
    const int gm   = m0 + srow;
    const int rmod = gm & (NROW - 1);
    const int wave = t >> 6;
    const int lane = t & 63;

    float cv[PP];
    #pragma unroll
    for (int i = 0; i < PP; ++i) cv[i] = cnt[i * NROW + rmod];

    const SrcT* aptr = src + (size_t)gm * DDIM + half * 16;
    // thread's fixed LDS slot: mtile = srow>>4, k-chunk quad = half*2 (+1 at +128 elems)
    unsigned short* sAw = &sA[(srow >> 4) * 512 + (half * 32 + (srow & 15)) * 8];

    floatx4 acc[4][4] = {};

    float va[16], vn[16];
    loadA16<SrcT>(va, aptr);                     // kb=0 columns

    for (int kb = 0; kb < 16; ++kb) {
        #pragma unroll
        for (int i = 0; i < PP; ++i) {
            __syncthreads();                      // prev iter's fragment reads done
            // B: async global->LDS, wave handles ntiles 2w,2w+1 (1KB each, coalesced)
            {
                const size_t base = (size_t)((i * 16 + kb) * 32 + nb * 8 + wave * 2);
                glds16(Wsw + (base + 0) * 512 + lane * 8, &sB[(wave * 2 + 0) * 512]);
                glds16(Wsw + (base + 1) * 512 + lane * 8, &sB[(wave * 2 + 1) * 512]);
            }
            // A: scale row by cnt_i, pack bf16, 2x ds_write_b128
            {
                const float c = cv[i];
                unsigned hp[8];
                #pragma unroll
                for (int j = 0; j < 8; ++j) hp[j] = pack_bf16(c * va[2*j], c * va[2*j+1]);
                uintx4 w0 = {hp[0], hp[1], hp[2], hp[3]};
                uintx4 w1 = {hp[4], hp[5], hp[6], hp[7]};
                *(uintx4*)sAw        = w0;
                *(uintx4*)(sAw + 128) = w1;
            }
            if (i == 0 && kb < 15) loadA16<SrcT>(vn, aptr + (kb + 1) * 32);   // prefetch
            __syncthreads();
            // fragments: conflict-free (base + lane*16B)
            short8 af[4], bfr[4];
            #pragma unroll
            for (int a = 0; a < 4; ++a)
                af[a] = *(const short8*)&sA[(((wave & 1) * 4 + a) * 64 + lane) * 8];
            #pragma unroll
            for (int b = 0; b < 4; ++b)
                bfr[b] = *(const short8*)&sB[(((wave >> 1) * 4 + b) * 64 + lane) * 8];
            #pragma unroll
            for (int a = 0; a < 4; ++a)
                #pragma unroll
                for (int b = 0; b < 4; ++b)
                    acc[a][b] = __builtin_amdgcn_mfma_f32_16x16x32_bf16(af[a], bfr[b], acc[a][b], 0, 0, 0);
        }
        #pragma unroll
        for (int j = 0; j < 16; ++j) va[j] = vn[j];
    }

    // epilogue: dst = src + scale*acc   (C/D: col=lane&15, row=(lane>>4)*4+reg)
    const int wm = (wave & 1) * 64, wn = (wave >> 1) * 64;
    const int lm = lane & 15, l4 = lane >> 4;
    #pragma unroll
    for (int a = 0; a < 4; ++a) {
        #pragma unroll
        for (int q = 0; q < 4; ++q) {
            const size_t om = (size_t)(m0 + wm + 16 * a + l4 * 4 + q);
            #pragma unroll
            for (int b = 0; b < 4; ++b) {
                const size_t on = (size_t)nb * 128 + wn + 16 * b + lm;
                const float up = loadF(src + om * DDIM + on);
                storeF(dst + om * DDIM + on, up + scale * acc[a][b][q]);
            }
        }
    }
}

extern "C" void kernel_launch(void* const* d_in, const int* in_sizes, int n_in,
                              void* d_out, int out_size, void* d_ws, size_t ws_size,
                              hipStream_t stream) {
    const float* x      = (const float*)d_in[0];   // (8, 8192, 512) fp32
    const float* W      = (const float*)d_in[1];   // (4, 512, 512) fp32
    const int*   groups = (const int*)d_in[2];     // (4, 512, 16) int32
    float* out = (float*)d_out;                    // (8, 8192, 512) fp32

    char* ws = (char*)d_ws;
    float*          cnt = (float*)ws;                               // 128 KB
    unsigned short* Wsw = (unsigned short*)(ws + 131072);           // 2 MB
    unsigned short* U   = (unsigned short*)(ws + 131072 + 2097152); // 64 MB bf16

    hipMemsetAsync(cnt, 0, PP * NROW * sizeof(float), stream);
    hist_kernel<<<32768 / 256, 256, 0, stream>>>(groups, cnt);
    transpose_w<<<131072 / 256, 256, 0, stream>>>(W, Wsw);

    dim3 grid(MTOT / 128, DDIM / 128);
    // round 1: x (fp32) -> out (fp32)
    gemm_round<float, float><<<grid, 256, 0, stream>>>(x, Wsw, cnt, out, 1.0f);
    // round 2: out (fp32) -> U (bf16)
    gemm_round<float, unsigned short><<<grid, 256, 0, stream>>>(out, Wsw, cnt, U, 0.5f);
    // round 3: U (bf16) -> out (fp32)
    gemm_round<unsigned short, float><<<grid, 256, 0, stream>>>(U, Wsw, cnt, out, 1.0f / 3.0f);
}